// Round 1
// baseline (3106.930 us; speedup 1.0000x reference)
//
#include <hip/hip_runtime.h>
#include <hip/hip_bf16.h>
#include <cstdint>
#include <cstddef>

// Problem constants
#define N_NODE 100000
#define N_EDGE 1600000
#define N_REL  4
#define DIM    128
#define CHUNK  2048
#define NCH    ((N_NODE + CHUNK - 1) / CHUNK)   // 49

// ---------------------------------------------------------------------------
// 1) Degree histogram (int atomics; avg 16 hits/bucket)
// ---------------------------------------------------------------------------
__global__ void k_count(const int* __restrict__ src, const int* __restrict__ dst,
                        int* __restrict__ cnt_out, int* __restrict__ cnt_in) {
    int r = blockIdx.y;
    int e = blockIdx.x * blockDim.x + threadIdx.x;
    if (e < N_EDGE) {
        int idx = r * N_EDGE + e;
        atomicAdd(&cnt_out[r * N_NODE + src[idx]], 1);
        atomicAdd(&cnt_in [r * N_NODE + dst[idx]], 1);
    }
}

// 2) rsqrt of clamped degrees
__global__ void k_rinv(const int* __restrict__ cnt_out, const int* __restrict__ cnt_in,
                       float* __restrict__ rinv_out, float* __restrict__ rinv_in) {
    int i = blockIdx.x * blockDim.x + threadIdx.x;
    if (i < N_REL * N_NODE) {
        rinv_out[i] = rsqrtf((float)max(cnt_out[i], 1));
        rinv_in[i]  = rsqrtf((float)max(cnt_in[i], 1));
    }
}

// ---------------------------------------------------------------------------
// 3) CSR-by-dst build: chunk sums -> scan partials -> chunk scan -> cursor
// ---------------------------------------------------------------------------
__global__ void k_chunk_sum(const int* __restrict__ cnt_in, int* __restrict__ partials) {
    int r = blockIdx.y, ch = blockIdx.x;
    __shared__ int sdata[256];
    int s = 0;
    for (int i = 0; i < CHUNK / 256; ++i) {
        int n = ch * CHUNK + i * 256 + threadIdx.x;
        if (n < N_NODE) s += cnt_in[r * N_NODE + n];
    }
    sdata[threadIdx.x] = s;
    __syncthreads();
    for (int off = 128; off > 0; off >>= 1) {
        if (threadIdx.x < off) sdata[threadIdx.x] += sdata[threadIdx.x + off];
        __syncthreads();
    }
    if (threadIdx.x == 0) partials[r * NCH + ch] = sdata[0];
}

__global__ void k_scan_partials(const int* __restrict__ partials,
                                int* __restrict__ chunk_base, int* __restrict__ row_ptr) {
    __shared__ int sp[N_REL * NCH];
    int t = threadIdx.x;
    if (t < N_REL * NCH) sp[t] = partials[t];
    __syncthreads();
    if (t == 0) {
        for (int r = 0; r < N_REL; ++r) {
            int run = 0;
            for (int ch = 0; ch < NCH; ++ch) {
                chunk_base[r * NCH + ch] = run;
                run += sp[r * NCH + ch];
            }
            row_ptr[r * (N_NODE + 1) + N_NODE] = N_EDGE;
        }
    }
}

__global__ void k_chunk_scan(const int* __restrict__ cnt_in,
                             const int* __restrict__ chunk_base, int* __restrict__ row_ptr) {
    int r = blockIdx.y, ch = blockIdx.x;
    __shared__ int tsum[256];
    int base_n = ch * CHUNK;
    int vals[8];
    int loc = 0;
    for (int i = 0; i < 8; ++i) {
        int n = base_n + threadIdx.x * 8 + i;
        vals[i] = (n < N_NODE) ? cnt_in[r * N_NODE + n] : 0;
        loc += vals[i];
    }
    tsum[threadIdx.x] = loc;
    __syncthreads();
    for (int off = 1; off < 256; off <<= 1) {     // Hillis-Steele inclusive scan
        int y = (threadIdx.x >= off) ? tsum[threadIdx.x - off] : 0;
        __syncthreads();
        tsum[threadIdx.x] += y;
        __syncthreads();
    }
    int pos = chunk_base[r * NCH + ch] + tsum[threadIdx.x] - loc;  // exclusive
    for (int i = 0; i < 8; ++i) {
        int n = base_n + threadIdx.x * 8 + i;
        if (n < N_NODE) { row_ptr[r * (N_NODE + 1) + n] = pos; pos += vals[i]; }
    }
}

__global__ void k_cursor(const int* __restrict__ row_ptr, int* __restrict__ cursor) {
    int i = blockIdx.x * blockDim.x + threadIdx.x;
    if (i < N_REL * N_NODE) {
        int r = i / N_NODE, n = i - r * N_NODE;
        cursor[i] = row_ptr[r * (N_NODE + 1) + n];
    }
}

// 4) Scatter edges into CSR slots with precomputed coefficient
//    c_e = ew * rinv_out[src] * rinv_in[dst]  (valid for BOTH layers)
__global__ void k_scatter(const int* __restrict__ src, const int* __restrict__ dst,
                          const float* __restrict__ ew,
                          const float* __restrict__ rinv_out, const float* __restrict__ rinv_in,
                          int* __restrict__ cursor,
                          int* __restrict__ src_s, float* __restrict__ c_s) {
    int r = blockIdx.y;
    int e = blockIdx.x * blockDim.x + threadIdx.x;
    if (e < N_EDGE) {
        int idx = r * N_EDGE + e;
        int s = src[idx], d = dst[idx];
        float c = ew[idx] * rinv_out[r * N_NODE + s] * rinv_in[r * N_NODE + d];
        int pos = atomicAdd(&cursor[r * N_NODE + d], 1);
        src_s[r * N_EDGE + pos] = s;
        c_s [r * N_EDGE + pos] = c;
    }
}

// ---------------------------------------------------------------------------
// 5) SpMM: tmp[n,:] = sum_{e in-edges of n} c_e * h[src_e,:]
//    one wave per dst node; lane owns 2 contiguous columns (float2) -> fully
//    coalesced 512B row gathers, register accumulation, no float atomics.
// ---------------------------------------------------------------------------
__global__ void k_spmm(const int* __restrict__ row_ptr, const int* __restrict__ src_s,
                       const float* __restrict__ c_s, const float* __restrict__ h,
                       float* __restrict__ tmp, int r) {
    int wave = threadIdx.x >> 6;
    int lane = threadIdx.x & 63;
    int node = blockIdx.x * 4 + wave;
    if (node >= N_NODE) return;
    int k0 = row_ptr[r * (N_NODE + 1) + node];
    int k1 = row_ptr[r * (N_NODE + 1) + node + 1];
    const int*   ss = src_s + r * N_EDGE;
    const float* cs = c_s  + r * N_EDGE;
    const float2* h2 = (const float2*)h;
    float2 acc = make_float2(0.f, 0.f);
    int k = k0;
    for (; k + 1 < k1; k += 2) {      // 2-deep to overlap dependent loads
        int   s0 = ss[k],     s1 = ss[k + 1];
        float c0 = cs[k],     c1 = cs[k + 1];
        float2 v0 = h2[s0 * 64 + lane];
        float2 v1 = h2[s1 * 64 + lane];
        acc.x += c0 * v0.x; acc.y += c0 * v0.y;
        acc.x += c1 * v1.x; acc.y += c1 * v1.y;
    }
    if (k < k1) {
        int s0 = ss[k]; float c0 = cs[k];
        float2 v0 = h2[s0 * 64 + lane];
        acc.x += c0 * v0.x; acc.y += c0 * v0.y;
    }
    ((float2*)tmp)[node * 64 + lane] = acc;
}

// ---------------------------------------------------------------------------
// 6) GEMM: out (op)= tmp[N,128] @ W[128,128]  (fp32 VALU; no fp32 MFMA on CDNA4)
//    mode 0: out = acc + sum_r b[r]   (first relation: init + bias)
//    mode 1: out += acc
//    mode 2: out = relu(out + acc)    (last relation)
//    Block 256 = 4 waves; wave = 16 rows, lane = 2 cols. W in LDS (64KB).
//    A-loads are wave-uniform float4 -> scalar loads; W LDS reads 2-way (free).
// ---------------------------------------------------------------------------
__global__ __launch_bounds__(256) void k_gemm(const float* __restrict__ A,
                                              const float* __restrict__ W,
                                              const float* __restrict__ b,
                                              float* __restrict__ out, int mode) {
    __shared__ float Wl[DIM * DIM];   // 64 KiB
    for (int i = 0; i < 64; ++i)
        Wl[threadIdx.x + i * 256] = W[threadIdx.x + i * 256];
    __syncthreads();

    int col  = threadIdx.x & 63;
    int rg   = threadIdx.x >> 6;
    int row0 = blockIdx.x * 64 + rg * 16;
    if (row0 >= N_NODE) return;   // N % 16 == 0 so rowgroups are full or empty

    float acc0[16], acc1[16];
#pragma unroll
    for (int i = 0; i < 16; ++i) { acc0[i] = 0.f; acc1[i] = 0.f; }

    for (int kb = 0; kb < DIM; kb += 4) {
        float4 a[16];
#pragma unroll
        for (int i = 0; i < 16; ++i)
            a[i] = *(const float4*)(A + (size_t)(row0 + i) * DIM + kb);
#pragma unroll
        for (int j = 0; j < 4; ++j) {
            float w0 = Wl[(kb + j) * DIM + col];
            float w1 = Wl[(kb + j) * DIM + col + 64];
#pragma unroll
            for (int i = 0; i < 16; ++i) {
                float av = (j == 0) ? a[i].x : (j == 1) ? a[i].y : (j == 2) ? a[i].z : a[i].w;
                acc0[i] += av * w0;
                acc1[i] += av * w1;
            }
        }
    }

    float bs0 = 0.f, bs1 = 0.f;
    if (mode == 0) {
#pragma unroll
        for (int r = 0; r < N_REL; ++r) {
            bs0 += b[r * DIM + col];
            bs1 += b[r * DIM + col + 64];
        }
    }
#pragma unroll
    for (int i = 0; i < 16; ++i) {
        size_t o = (size_t)(row0 + i) * DIM + col;
        if (mode == 0) {
            out[o]      = acc0[i] + bs0;
            out[o + 64] = acc1[i] + bs1;
        } else if (mode == 1) {
            out[o]      += acc0[i];
            out[o + 64] += acc1[i];
        } else {
            float v0 = out[o]      + acc0[i];
            float v1 = out[o + 64] + acc1[i];
            out[o]      = v0 > 0.f ? v0 : 0.f;
            out[o + 64] = v1 > 0.f ? v1 : 0.f;
        }
    }
}

// ---------------------------------------------------------------------------
extern "C" void kernel_launch(void* const* d_in, const int* in_sizes, int n_in,
                              void* d_out, int out_size, void* d_ws, size_t ws_size,
                              hipStream_t stream) {
    const float* x   = (const float*)d_in[0];
    const int*   src = (const int*)  d_in[1];
    const int*   dst = (const int*)  d_in[2];
    const float* ew  = (const float*)d_in[3];
    const float* W1  = (const float*)d_in[4];
    const float* b1  = (const float*)d_in[5];
    const float* W2  = (const float*)d_in[6];
    const float* b2  = (const float*)d_in[7];
    float* out = (float*)d_out;

    // Workspace carve-up (~163 MB, everything rewritten each launch)
    char* p = (char*)d_ws;
    auto alloc = [&](size_t bytes) -> char* {
        char* q = p;
        p += (bytes + 255) & ~(size_t)255;
        return q;
    };
    const size_t RN = (size_t)N_REL * N_NODE;
    int*   cnt_out    = (int*)  alloc(RN * 4);
    int*   cnt_in     = (int*)  alloc(RN * 4);
    float* rinv_out   = (float*)alloc(RN * 4);
    float* rinv_in    = (float*)alloc(RN * 4);
    int*   row_ptr    = (int*)  alloc((size_t)N_REL * (N_NODE + 1) * 4);
    int*   cursor     = (int*)  alloc(RN * 4);
    int*   partials   = (int*)  alloc(N_REL * NCH * 4);
    int*   chunk_base = (int*)  alloc(N_REL * NCH * 4);
    int*   src_s      = (int*)  alloc((size_t)N_REL * N_EDGE * 4);
    float* c_s        = (float*)alloc((size_t)N_REL * N_EDGE * 4);
    float* tmp        = (float*)alloc((size_t)N_NODE * DIM * 4);
    float* h_mid      = (float*)alloc((size_t)N_NODE * DIM * 4);

    // zero the histograms (cnt_out, cnt_in are adjacent)
    hipMemsetAsync(cnt_out, 0, 2 * ((RN * 4 + 255) & ~(size_t)255), stream);

    dim3 gridE((N_EDGE + 255) / 256, N_REL);
    k_count<<<gridE, 256, 0, stream>>>(src, dst, cnt_out, cnt_in);
    k_rinv<<<(RN + 255) / 256, 256, 0, stream>>>(cnt_out, cnt_in, rinv_out, rinv_in);
    k_chunk_sum<<<dim3(NCH, N_REL), 256, 0, stream>>>(cnt_in, partials);
    k_scan_partials<<<1, 256, 0, stream>>>(partials, chunk_base, row_ptr);
    k_chunk_scan<<<dim3(NCH, N_REL), 256, 0, stream>>>(cnt_in, chunk_base, row_ptr);
    k_cursor<<<(RN + 255) / 256, 256, 0, stream>>>(row_ptr, cursor);
    k_scatter<<<gridE, 256, 0, stream>>>(src, dst, ew, rinv_out, rinv_in, cursor, src_s, c_s);

    const int spmm_grid = (N_NODE + 3) / 4;
    const int gemm_grid = (N_NODE + 63) / 64;

    // layer 1: x -> h_mid
    for (int r = 0; r < N_REL; ++r) {
        k_spmm<<<spmm_grid, 256, 0, stream>>>(row_ptr, src_s, c_s, x, tmp, r);
        int mode = (r == 0) ? 0 : (r == N_REL - 1 ? 2 : 1);
        k_gemm<<<gemm_grid, 256, 0, stream>>>(tmp, W1 + (size_t)r * DIM * DIM, b1, h_mid, mode);
    }
    // layer 2: h_mid -> out
    for (int r = 0; r < N_REL; ++r) {
        k_spmm<<<spmm_grid, 256, 0, stream>>>(row_ptr, src_s, c_s, h_mid, tmp, r);
        int mode = (r == 0) ? 0 : (r == N_REL - 1 ? 2 : 1);
        k_gemm<<<gemm_grid, 256, 0, stream>>>(tmp, W2 + (size_t)r * DIM * DIM, b2, out, mode);
    }
}